// Round 6
// baseline (77.114 us; speedup 1.0000x reference)
//
#include <hip/hip_runtime.h>

#define TWO_LOG2E 2.8853900817779268f

__device__ __forceinline__ float frcp(float x) {
#if __has_builtin(__builtin_amdgcn_rcpf)
  return __builtin_amdgcn_rcpf(x);
#else
  return 1.0f / x;
#endif
}
__device__ __forceinline__ float fexp2(float x) {
#if __has_builtin(__builtin_amdgcn_exp2f)
  return __builtin_amdgcn_exp2f(x);
#else
  return exp2f(x);
#endif
}
__device__ __forceinline__ unsigned short f2bf(float f) {  // RNE f32->bf16
  unsigned int u = __float_as_uint(f);
  u += 0x7fffu + ((u >> 16) & 1u);
  return (unsigned short)(u >> 16);
}
__device__ __forceinline__ unsigned int pack2bf(float lo, float hi) {
  return (unsigned int)f2bf(lo) | ((unsigned int)f2bf(hi) << 16);
}

using short8 = __attribute__((ext_vector_type(8))) short;
using f32x4v = __attribute__((ext_vector_type(4))) float;

// ---------------------------------------------------------------------------
// K1: Aexp = exp(2*query@w1^T) (f32), Bexp = exp(2*key@w2^T) (bf16)
// via bf16 MFMA 16x16x32. M=4096, N=128, K=512. BM=32, BN=64, BK=64.
// grid (128, 2, 2), block 256 (4 waves: wr = m-half(16), wc = n-half(32)).
// ---------------------------------------------------------------------------
__global__ __launch_bounds__(256) void k_proj_mfma(
    const float* __restrict__ query, const float* __restrict__ key,
    const float* __restrict__ w1, const float* __restrict__ w2,
    float* __restrict__ Aout, unsigned short* __restrict__ Bout) {
  const float* in = blockIdx.z ? key : query;
  const float* wm = blockIdx.z ? w2  : w1;

  __shared__ __align__(16) char Abuf[32 * 128];  // [m][k] bf16, swizzled, 4KB
  __shared__ __align__(16) char Bbuf[64 * 128];  // [n][k] bf16, swizzled, 8KB

  const int t = threadIdx.x;
  const int m0g = blockIdx.x * 32;
  const int n0g = blockIdx.y * 64;
  const int w = t >> 6, l = t & 63;
  const int wr = w >> 1, wc = w & 1;

  f32x4v acc[2];
  acc[0] = 0;
  acc[1] = 0;

  const int srow = t >> 3, sg = t & 7;  // staging: row, granule

  for (int k0 = 0; k0 < 512; k0 += 64) {
    if (k0) __syncthreads();
    {  // stage A tile 32m x 64k: 1 granule (8 floats -> 8 bf16) per thread
      const float* src = &in[(m0g + srow) * 512 + k0 + sg * 8];
      float4 f0 = *(const float4*)src;
      float4 f1 = *(const float4*)(src + 4);
      uint4 p = make_uint4(pack2bf(f0.x, f0.y), pack2bf(f0.z, f0.w),
                           pack2bf(f1.x, f1.y), pack2bf(f1.z, f1.w));
      *(uint4*)(Abuf + srow * 128 + ((sg ^ (srow & 7)) << 4)) = p;
    }
#pragma unroll
    for (int i = 0; i < 2; ++i) {  // stage B(w) tile 64n x 64k: 2 granules/thread
      int row = srow + 32 * i;
      const float* src = &wm[(n0g + row) * 512 + k0 + sg * 8];
      float4 f0 = *(const float4*)src;
      float4 f1 = *(const float4*)(src + 4);
      uint4 p = make_uint4(pack2bf(f0.x, f0.y), pack2bf(f0.z, f0.w),
                           pack2bf(f1.x, f1.y), pack2bf(f1.z, f1.w));
      *(uint4*)(Bbuf + row * 128 + ((sg ^ (row & 7)) << 4)) = p;
    }
    __syncthreads();
#pragma unroll
    for (int ks = 0; ks < 2; ++ks) {
      const int gb = ks * 4 + (l >> 4);
      int ra = wr * 16 + (l & 15);
      short8 af = *(const short8*)(Abuf + ra * 128 + ((gb ^ (ra & 7)) << 4));
#pragma unroll
      for (int ni = 0; ni < 2; ++ni) {
        int rb = wc * 32 + ni * 16 + (l & 15);
        short8 bf_ = *(const short8*)(Bbuf + rb * 128 + ((gb ^ (rb & 7)) << 4));
        acc[ni] = __builtin_amdgcn_mfma_f32_16x16x32_bf16(af, bf_, acc[ni], 0, 0, 0);
      }
    }
  }
#pragma unroll
  for (int ni = 0; ni < 2; ++ni) {
    int col = n0g + wc * 32 + ni * 16 + (l & 15);
#pragma unroll
    for (int j = 0; j < 4; ++j) {
      int row = m0g + wr * 16 + (l >> 4) * 4 + j;
      float val = fexp2(acc[ni][j] * TWO_LOG2E);
      if (blockIdx.z == 0)
        Aout[row * 128 + col] = val;
      else
        Bout[row * 128 + col] = f2bf(val);
    }
  }
}

// ---------------------------------------------------------------------------
// k_valT: valT[b][n][k] = bf16(value[b][k][n]).  64x64 tiles, grid (8,8,8).
// ---------------------------------------------------------------------------
__global__ __launch_bounds__(256) void k_valT(
    const float* __restrict__ value, unsigned short* __restrict__ valT) {
  __shared__ unsigned short ts[64][66];
  const int t = threadIdx.x;
  const int b = blockIdx.z, k0 = blockIdx.y * 64, n0 = blockIdx.x * 64;
  {
    int kr = t >> 4, n4 = (t & 15) * 4;
#pragma unroll
    for (int i = 0; i < 4; ++i) {
      float4 f = *(const float4*)&value[((b * 512) + k0 + kr + 16 * i) * 512 + n0 + n4];
      *(ushort4*)&ts[kr + 16 * i][n4] =
          make_ushort4(f2bf(f.x), f2bf(f.y), f2bf(f.z), f2bf(f.w));
    }
  }
  __syncthreads();
  {
    int nw = t >> 4, k4 = (t & 15) * 4;
#pragma unroll
    for (int i = 0; i < 4; ++i) {
      int n = nw + 16 * i;
      ushort4 o = make_ushort4(ts[k4 + 0][n], ts[k4 + 1][n], ts[k4 + 2][n], ts[k4 + 3][n]);
      *(ushort4*)&valT[((b * 512) + n0 + n) * 512 + k0 + k4] = o;
    }
  }
}

// ---------------------------------------------------------------------------
// K2: S[q,k] = sum_h v[h]/(A[q,h]*B[k,h]+1);  attn = softmax_k(-2S).
// A,v staged ONCE into a 2.5KB LDS table, read per-hg as uniform-address
// LDS broadcasts (no global loads in the hot loop). B (per-lane k) in LDS
// bf16, XOR-swizzled, T14-pipelined. Pair-4 rcp.
// 4 q-rows/block, 4 waves = (row-pair, k-half). grid (128, 8), block 256.
// ---------------------------------------------------------------------------
__global__ __launch_bounds__(256) void k_score_softmax(
    const float* __restrict__ Aexp, const unsigned short* __restrict__ Bexp,
    const float* __restrict__ vw, float* __restrict__ attn) {
  __shared__ __align__(16) char Bt_raw[128 * 256];  // [k][h] bf16, swizzled, 32KB
  __shared__ __align__(16) float av[32 * 20];       // [hg][a0q a1q a2q a3q vq]
  __shared__ float red[4][2];

  const int tid = threadIdx.x;
  const int b = blockIdx.y;
  const int qbase = blockIdx.x * 4;
  const int wav = tid >> 6;
  const int lane = tid & 63;
  const int rp = wav >> 1;   // row pair 0..1
  const int kh = wav & 1;    // k half 0..1
  const int klocal = kh * 64 + lane;
  // read addressing: lane-swizzle folded into base; per-hg addr = roff0 ^ (hg<<3)
  const int roff0 = klocal * 256 + ((klocal & 31) << 3);

  // B staging addressing (write side): row kr, h-segment hseg
  const int kr = tid >> 1;
  const int hseg = (tid & 1) * 64;
  const int woff0 = kr * 256 + ((((hseg >> 2)) ^ (kr & 31)) << 3);
  const unsigned short* const bsrc0 = Bexp + (b * 512 + kr) * 128 + hseg;

  uint4 stg[8];
#define K2_LOADS(kt_)                                                     \
  {                                                                       \
    const uint4* s_ = (const uint4*)(bsrc0 + (kt_) * 16384);              \
    _Pragma("unroll") for (int j = 0; j < 8; ++j) stg[j] = s_[j];         \
  }
#define K2_WRITE()                                                        \
  {                                                                       \
    _Pragma("unroll") for (int j = 0; j < 8; ++j) {                       \
      int off_ = woff0 ^ (j << 4);                                        \
      *(uint2*)(Bt_raw + off_) = make_uint2(stg[j].x, stg[j].y);          \
      *(uint2*)(Bt_raw + (off_ ^ 8)) = make_uint2(stg[j].z, stg[j].w);    \
    }                                                                     \
  }

  // stage A/v table (once): 160 chunks of 16B. av[hg][aq]: aq 0..3 = A rows
  // qbase+0..3 (elements hg*4..hg*4+3), aq=4 = v[hg*4..hg*4+3].
  float4 avreg;
  int avdst = 0;
  if (tid < 160) {
    int ahg = tid / 5;          // compiler emits exact magic-multiply
    int aq = tid - ahg * 5;
    const float* src = (aq < 4) ? &Aexp[(b * 512 + qbase + aq) * 128 + ahg * 4]
                                : &vw[ahg * 4];
    avreg = *(const float4*)src;
    avdst = ahg * 20 + aq * 4;
  }
  K2_LOADS(0);
  if (tid < 160) *(float4*)&av[avdst] = avreg;
  K2_WRITE();
  __syncthreads();

  float S0[4], S1[4];
#pragma unroll
  for (int kt = 0; kt < 4; ++kt) {
    if (kt < 3) K2_LOADS(kt + 1);  // in flight under compute
    float s0 = 0.f, s1 = 0.f;
#pragma unroll 8
    for (int hg = 0; hg < 32; ++hg) {
      unsigned long long u =
          *(const unsigned long long*)(Bt_raw + (roff0 ^ (hg << 3)));
      const float* avp = &av[hg * 20 + rp * 8];
      float4 a0 = *(const float4*)avp;                  // LDS broadcast
      float4 a1 = *(const float4*)(avp + 4);            // LDS broadcast
      float4 v4 = *(const float4*)(&av[hg * 20] + 16);  // LDS broadcast
      unsigned int lo = (unsigned int)u, hi = (unsigned int)(u >> 32);
      float b0 = __uint_as_float(lo << 16);
      float b1 = __uint_as_float(lo & 0xffff0000u);
      float b2 = __uint_as_float(hi << 16);
      float b3 = __uint_as_float(hi & 0xffff0000u);
      {  // row 0: sum_{i=0..3} v_i/x_i with ONE rcp
        float x0 = fmaf(a0.x, b0, 1.f), x1 = fmaf(a0.y, b1, 1.f);
        float x2 = fmaf(a0.z, b2, 1.f), x3 = fmaf(a0.w, b3, 1.f);
        float p01 = x0 * x1, p23 = x2 * x3;
        float n01 = fmaf(v4.x, x1, v4.y * x0);
        float n23 = fmaf(v4.z, x3, v4.w * x2);
        float num = fmaf(n01, p23, n23 * p01);
        s0 = fmaf(num, frcp(p01 * p23), s0);
      }
      {  // row 1
        float x0 = fmaf(a1.x, b0, 1.f), x1 = fmaf(a1.y, b1, 1.f);
        float x2 = fmaf(a1.z, b2, 1.f), x3 = fmaf(a1.w, b3, 1.f);
        float p01 = x0 * x1, p23 = x2 * x3;
        float n01 = fmaf(v4.x, x1, v4.y * x0);
        float n23 = fmaf(v4.z, x3, v4.w * x2);
        float num = fmaf(n01, p23, n23 * p01);
        s1 = fmaf(num, frcp(p01 * p23), s1);
      }
    }
    S0[kt] = s0;
    S1[kt] = s1;
    if (kt < 3) {
      __syncthreads();  // all reads of Bt done
      K2_WRITE();       // vmcnt wait inserted by compiler
      __syncthreads();  // Bt ready
    }
  }
#undef K2_LOADS
#undef K2_WRITE

  // softmax over k of (-2S): max(score) <-> min(S). Rows span 2 waves (k-halves).
  float mn0 = fminf(fminf(S0[0], S0[1]), fminf(S0[2], S0[3]));
  float mn1 = fminf(fminf(S1[0], S1[1]), fminf(S1[2], S1[3]));
#pragma unroll
  for (int off = 32; off > 0; off >>= 1) {
    mn0 = fminf(mn0, __shfl_xor(mn0, off));
    mn1 = fminf(mn1, __shfl_xor(mn1, off));
  }
  if (lane == 0) { red[wav][0] = mn0; red[wav][1] = mn1; }
  __syncthreads();
  mn0 = fminf(red[wav][0], red[wav ^ 1][0]);
  mn1 = fminf(red[wav][1], red[wav ^ 1][1]);
  __syncthreads();  // before red reuse

  float P0[4], P1[4];
  float sum0 = 0.f, sum1 = 0.f;
#pragma unroll
  for (int kt = 0; kt < 4; ++kt) {
    P0[kt] = fexp2((mn0 - S0[kt]) * TWO_LOG2E);
    P1[kt] = fexp2((mn1 - S1[kt]) * TWO_LOG2E);
    sum0 += P0[kt];
    sum1 += P1[kt];
  }
#pragma unroll
  for (int off = 32; off > 0; off >>= 1) {
    sum0 += __shfl_xor(sum0, off);
    sum1 += __shfl_xor(sum1, off);
  }
  if (lane == 0) { red[wav][0] = sum0; red[wav][1] = sum1; }
  __syncthreads();
  float r0 = frcp(red[wav][0] + red[wav ^ 1][0]);
  float r1 = frcp(red[wav][1] + red[wav ^ 1][1]);

  const int row0 = (b * 512 + qbase + rp * 2) * 512;
#pragma unroll
  for (int kt = 0; kt < 4; ++kt) {
    int kcol = kt * 128 + kh * 64 + lane;
    attn[row0 + kcol] = P0[kt] * r0;
    attn[row0 + 512 + kcol] = P1[kt] * r1;
  }
}

// ---------------------------------------------------------------------------
// K3: context[b] = attn[b] @ value[b] via bf16 MFMA 16x16x32.
// Tile 64x64, BK=64, 4 waves (2x2), wave tile 32x32 (2x2 frags).
// grid (8,8,8), block 256.
// ---------------------------------------------------------------------------
__global__ __launch_bounds__(256) void k_context_mfma(
    const float* __restrict__ attn, const unsigned short* __restrict__ valT,
    float* __restrict__ ctx) {
  __shared__ __align__(16) char At[64 * 128];  // [m][k] bf16 swizzled, 8KB
  __shared__ __align__(16) char Bt[64 * 128];  // [n][k] bf16 swizzled, 8KB

  const int t = threadIdx.x;
  const int b = blockIdx.z;
  const int m0 = blockIdx.y * 64, n0 = blockIdx.x * 64;
  const int w = t >> 6, l = t & 63;
  const int wr = w >> 1, wc = w & 1;

  f32x4v acc[2][2];
  acc[0][0] = 0; acc[0][1] = 0; acc[1][0] = 0; acc[1][1] = 0;

  const int sr = t >> 2;
  const int sg = (t & 3);
  const int sswz = sr & 7;

  for (int k0 = 0; k0 < 512; k0 += 64) {
    if (k0) __syncthreads();
    {  // stage A: 16 f32 -> 16 bf16 per thread
      const float* src = &attn[(b * 512 + m0 + sr) * 512 + k0 + sg * 16];
      char* dst = At + sr * 128;
#pragma unroll
      for (int h = 0; h < 2; ++h) {
        float4 f0 = *(const float4*)(src + h * 8);
        float4 f1 = *(const float4*)(src + h * 8 + 4);
        uint4 p = make_uint4(pack2bf(f0.x, f0.y), pack2bf(f0.z, f0.w),
                             pack2bf(f1.x, f1.y), pack2bf(f1.z, f1.w));
        int g = sg * 2 + h;
        *(uint4*)(dst + ((g ^ sswz) << 4)) = p;
      }
      // stage B^T: 32 bf16 per thread (already bf16)
      const unsigned short* srcb = &valT[(b * 512 + n0 + sr) * 512 + k0];
      char* dstb = Bt + sr * 128;
#pragma unroll
      for (int h = 0; h < 2; ++h) {
        int g = sg + h * 4;
        uint4 vb = *(const uint4*)(srcb + g * 8);
        *(uint4*)(dstb + ((g ^ sswz) << 4)) = vb;
      }
    }
    __syncthreads();
#pragma unroll
    for (int ks = 0; ks < 2; ++ks) {
      const int gb = ks * 4 + (l >> 4);
      short8 af[2], bf_[2];
#pragma unroll
      for (int mi = 0; mi < 2; ++mi) {
        int ra = wr * 32 + mi * 16 + (l & 15);
        af[mi] = *(const short8*)(At + ra * 128 + ((gb ^ (ra & 7)) << 4));
      }
#pragma unroll
      for (int ni = 0; ni < 2; ++ni) {
        int rb = wc * 32 + ni * 16 + (l & 15);
        bf_[ni] = *(const short8*)(Bt + rb * 128 + ((gb ^ (rb & 7)) << 4));
      }
#pragma unroll
      for (int mi = 0; mi < 2; ++mi)
#pragma unroll
        for (int ni = 0; ni < 2; ++ni)
          acc[mi][ni] = __builtin_amdgcn_mfma_f32_16x16x32_bf16(
              af[mi], bf_[ni], acc[mi][ni], 0, 0, 0);
    }
  }
  __syncthreads();
#pragma unroll
  for (int mi = 0; mi < 2; ++mi)
#pragma unroll
    for (int ni = 0; ni < 2; ++ni) {
      int col = n0 + wc * 32 + ni * 16 + (l & 15);
#pragma unroll
      for (int j = 0; j < 4; ++j) {
        int row = m0 + wr * 32 + mi * 16 + (l >> 4) * 4 + j;
        ctx[(b * 512 + row) * 512 + col] = acc[mi][ni][j];
      }
    }
}

extern "C" void kernel_launch(void* const* d_in, const int* in_sizes, int n_in,
                              void* d_out, int out_size, void* d_ws, size_t ws_size,
                              hipStream_t stream) {
  const float* query = (const float*)d_in[0];
  const float* key   = (const float*)d_in[1];
  const float* value = (const float*)d_in[2];
  const float* w1    = (const float*)d_in[3];
  const float* w2    = (const float*)d_in[4];
  const float* v     = (const float*)d_in[5];

  float* attn = (float*)d_out;
  float* ctx  = attn + 8 * 512 * 512;

  float* Aexp = (float*)d_ws;                                   // 4096*128 f32
  unsigned short* Bexp = (unsigned short*)(Aexp + 4096 * 128);  // 4096*128 bf16
  unsigned short* valT = Bexp + 4096 * 128;                     // 8*512*512 bf16

  k_proj_mfma<<<dim3(128, 2, 2), 256, 0, stream>>>(query, key, w1, w2, Aexp, Bexp);
  k_valT<<<dim3(8, 8, 8), 256, 0, stream>>>(value, valT);
  k_score_softmax<<<dim3(128, 8), 256, 0, stream>>>(Aexp, Bexp, v, attn);
  k_context_mfma<<<dim3(8, 8, 8), 256, 0, stream>>>(attn, valT, ctx);
}

// Round 7
// 70.585 us; speedup vs baseline: 1.0925x; 1.0925x over previous
//
#include <hip/hip_runtime.h>

#define TWO_LOG2E 2.8853900817779268f

__device__ __forceinline__ float frcp(float x) {
#if __has_builtin(__builtin_amdgcn_rcpf)
  return __builtin_amdgcn_rcpf(x);
#else
  return 1.0f / x;
#endif
}
__device__ __forceinline__ float fexp2(float x) {
#if __has_builtin(__builtin_amdgcn_exp2f)
  return __builtin_amdgcn_exp2f(x);
#else
  return exp2f(x);
#endif
}
__device__ __forceinline__ unsigned short f2bf(float f) {  // RNE f32->bf16
  unsigned int u = __float_as_uint(f);
  u += 0x7fffu + ((u >> 16) & 1u);
  return (unsigned short)(u >> 16);
}
__device__ __forceinline__ unsigned int pack2bf(float lo, float hi) {
  return (unsigned int)f2bf(lo) | ((unsigned int)f2bf(hi) << 16);
}

using short8 = __attribute__((ext_vector_type(8))) short;
using f32x4v = __attribute__((ext_vector_type(4))) float;
using f32x8s = __attribute__((ext_vector_type(8))) float;

// ---------------------------------------------------------------------------
// K1: Aexp = exp(2*query@w1^T) (f32), Bexp = exp(2*key@w2^T) (bf16)
// via bf16 MFMA 16x16x32. M=4096, N=128, K=512. BM=32, BN=64, BK=64.
// grid (128, 2, 2), block 256 (4 waves: wr = m-half(16), wc = n-half(32)).
// ---------------------------------------------------------------------------
__global__ __launch_bounds__(256) void k_proj_mfma(
    const float* __restrict__ query, const float* __restrict__ key,
    const float* __restrict__ w1, const float* __restrict__ w2,
    float* __restrict__ Aout, unsigned short* __restrict__ Bout) {
  const float* in = blockIdx.z ? key : query;
  const float* wm = blockIdx.z ? w2  : w1;

  __shared__ __align__(16) char Abuf[32 * 128];  // [m][k] bf16, swizzled, 4KB
  __shared__ __align__(16) char Bbuf[64 * 128];  // [n][k] bf16, swizzled, 8KB

  const int t = threadIdx.x;
  const int m0g = blockIdx.x * 32;
  const int n0g = blockIdx.y * 64;
  const int w = t >> 6, l = t & 63;
  const int wr = w >> 1, wc = w & 1;

  f32x4v acc[2];
  acc[0] = 0;
  acc[1] = 0;

  const int srow = t >> 3, sg = t & 7;  // staging: row, granule

  for (int k0 = 0; k0 < 512; k0 += 64) {
    if (k0) __syncthreads();
    {  // stage A tile 32m x 64k: 1 granule (8 floats -> 8 bf16) per thread
      const float* src = &in[(m0g + srow) * 512 + k0 + sg * 8];
      float4 f0 = *(const float4*)src;
      float4 f1 = *(const float4*)(src + 4);
      uint4 p = make_uint4(pack2bf(f0.x, f0.y), pack2bf(f0.z, f0.w),
                           pack2bf(f1.x, f1.y), pack2bf(f1.z, f1.w));
      *(uint4*)(Abuf + srow * 128 + ((sg ^ (srow & 7)) << 4)) = p;
    }
#pragma unroll
    for (int i = 0; i < 2; ++i) {  // stage B(w) tile 64n x 64k: 2 granules/thread
      int row = srow + 32 * i;
      const float* src = &wm[(n0g + row) * 512 + k0 + sg * 8];
      float4 f0 = *(const float4*)src;
      float4 f1 = *(const float4*)(src + 4);
      uint4 p = make_uint4(pack2bf(f0.x, f0.y), pack2bf(f0.z, f0.w),
                           pack2bf(f1.x, f1.y), pack2bf(f1.z, f1.w));
      *(uint4*)(Bbuf + row * 128 + ((sg ^ (row & 7)) << 4)) = p;
    }
    __syncthreads();
#pragma unroll
    for (int ks = 0; ks < 2; ++ks) {
      const int gb = ks * 4 + (l >> 4);
      int ra = wr * 16 + (l & 15);
      short8 af = *(const short8*)(Abuf + ra * 128 + ((gb ^ (ra & 7)) << 4));
#pragma unroll
      for (int ni = 0; ni < 2; ++ni) {
        int rb = wc * 32 + ni * 16 + (l & 15);
        short8 bf_ = *(const short8*)(Bbuf + rb * 128 + ((gb ^ (rb & 7)) << 4));
        acc[ni] = __builtin_amdgcn_mfma_f32_16x16x32_bf16(af, bf_, acc[ni], 0, 0, 0);
      }
    }
  }
#pragma unroll
  for (int ni = 0; ni < 2; ++ni) {
    int col = n0g + wc * 32 + ni * 16 + (l & 15);
#pragma unroll
    for (int j = 0; j < 4; ++j) {
      int row = m0g + wr * 16 + (l >> 4) * 4 + j;
      float val = fexp2(acc[ni][j] * TWO_LOG2E);
      if (blockIdx.z == 0)
        Aout[row * 128 + col] = val;
      else
        Bout[row * 128 + col] = f2bf(val);
    }
  }
}

// ---------------------------------------------------------------------------
// k_valT: valT[b][n][k] = bf16(value[b][k][n]).  64x64 tiles, grid (8,8,8).
// ---------------------------------------------------------------------------
__global__ __launch_bounds__(256) void k_valT(
    const float* __restrict__ value, unsigned short* __restrict__ valT) {
  __shared__ unsigned short ts[64][66];
  const int t = threadIdx.x;
  const int b = blockIdx.z, k0 = blockIdx.y * 64, n0 = blockIdx.x * 64;
  {
    int kr = t >> 4, n4 = (t & 15) * 4;
#pragma unroll
    for (int i = 0; i < 4; ++i) {
      float4 f = *(const float4*)&value[((b * 512) + k0 + kr + 16 * i) * 512 + n0 + n4];
      *(ushort4*)&ts[kr + 16 * i][n4] =
          make_ushort4(f2bf(f.x), f2bf(f.y), f2bf(f.z), f2bf(f.w));
    }
  }
  __syncthreads();
  {
    int nw = t >> 4, k4 = (t & 15) * 4;
#pragma unroll
    for (int i = 0; i < 4; ++i) {
      int n = nw + 16 * i;
      ushort4 o = make_ushort4(ts[k4 + 0][n], ts[k4 + 1][n], ts[k4 + 2][n], ts[k4 + 3][n]);
      *(ushort4*)&valT[((b * 512) + n0 + n) * 512 + k0 + k4] = o;
    }
  }
}

// ---------------------------------------------------------------------------
// K2: S[q,k] = sum_h v[h]/(A[q,h]*B[k,h]+1);  attn = softmax_k(-2S).
// A,v fetched on the SCALAR (SMEM) pipe via inline-asm s_load_dwordx8 into
// SGPRs (wave-uniform operands; free as VALU srcs). Only B (per-lane k) goes
// through LDS (bf16, XOR-swizzled, T14-pipelined). Pair-4 rcp.
// 4 q-rows/block, 4 waves = (row-pair, k-half). grid (128, 8), block 256.
// ---------------------------------------------------------------------------
__global__ __launch_bounds__(256) void k_score_softmax(
    const float* __restrict__ Aexp, const unsigned short* __restrict__ Bexp,
    const float* __restrict__ vw, float* __restrict__ attn) {
  __shared__ __align__(16) char Bt_raw[128 * 256];  // [k][h] bf16, swizzled, 32KB
  __shared__ float red[4][2];

  const int tid = threadIdx.x;
  const int b = blockIdx.y;
  const int qbase = blockIdx.x * 4;
  const int wav = tid >> 6;
  const int lane = tid & 63;
  const int rp = wav >> 1;   // row pair 0..1
  const int kh = wav & 1;    // k half 0..1
  const int klocal = kh * 64 + lane;
  // read addressing: lane-swizzle folded into base; per-hg addr = roff0 ^ (hg<<3)
  const int roff0 = klocal * 256 + ((klocal & 31) << 3);

  // B staging addressing (write side): row kr, h-segment hseg
  const int kr = tid >> 1;
  const int hseg = (tid & 1) * 64;
  const int woff0 = kr * 256 + ((((hseg >> 2)) ^ (kr & 31)) << 3);
  const unsigned short* const bsrc0 = Bexp + (b * 512 + kr) * 128 + hseg;

  // wave-uniform scalar base pointers for A rows and v
  const float* const pa0 =
      Aexp + __builtin_amdgcn_readfirstlane((b * 512 + qbase + rp * 2) * 128);
  const float* const pa1 = pa0 + 128;
  const float* const pv = vw;

  uint4 stg[8];
#define K2_LOADS(kt_)                                                     \
  {                                                                       \
    const uint4* s_ = (const uint4*)(bsrc0 + (kt_) * 16384);              \
    _Pragma("unroll") for (int j = 0; j < 8; ++j) stg[j] = s_[j];         \
  }
#define K2_WRITE()                                                        \
  {                                                                       \
    _Pragma("unroll") for (int j = 0; j < 8; ++j) {                       \
      int off_ = woff0 ^ (j << 4);                                        \
      *(uint2*)(Bt_raw + off_) = make_uint2(stg[j].x, stg[j].y);          \
      *(uint2*)(Bt_raw + (off_ ^ 8)) = make_uint2(stg[j].z, stg[j].w);    \
    }                                                                     \
  }

  K2_LOADS(0);
  K2_WRITE();
  __syncthreads();

  float S0[4], S1[4];
#pragma unroll
  for (int kt = 0; kt < 4; ++kt) {
    if (kt < 3) K2_LOADS(kt + 1);  // in flight under compute
    float s0 = 0.f, s1 = 0.f;
#pragma unroll 2
    for (int hc = 0; hc < 16; ++hc) {  // chunk = 8 h-values = 2 hg
      f32x8s sa0, sa1, sv;
      unsigned soff = (unsigned)(hc * 32);  // byte offset, wave-uniform
      asm volatile(
          "s_load_dwordx8 %0, %3, %6\n\t"
          "s_load_dwordx8 %1, %4, %6\n\t"
          "s_load_dwordx8 %2, %5, %6\n\t"
          "s_waitcnt lgkmcnt(0)"
          : "=&s"(sa0), "=&s"(sa1), "=&s"(sv)
          : "s"(pa0), "s"(pa1), "s"(pv), "s"(soff));
#pragma unroll
      for (int j = 0; j < 2; ++j) {
        const int hg = hc * 2 + j;
        unsigned long long u =
            *(const unsigned long long*)(Bt_raw + (roff0 ^ (hg << 3)));
        unsigned int lo = (unsigned int)u, hi = (unsigned int)(u >> 32);
        float b0 = __uint_as_float(lo << 16);
        float b1 = __uint_as_float(lo & 0xffff0000u);
        float b2 = __uint_as_float(hi << 16);
        float b3 = __uint_as_float(hi & 0xffff0000u);
        const float a00 = sa0[j * 4 + 0], a01 = sa0[j * 4 + 1];
        const float a02 = sa0[j * 4 + 2], a03 = sa0[j * 4 + 3];
        const float a10 = sa1[j * 4 + 0], a11 = sa1[j * 4 + 1];
        const float a12 = sa1[j * 4 + 2], a13 = sa1[j * 4 + 3];
        const float v0 = sv[j * 4 + 0], v1 = sv[j * 4 + 1];
        const float v2 = sv[j * 4 + 2], v3 = sv[j * 4 + 3];
        {  // row 0: sum_{i=0..3} v_i/x_i with ONE rcp
          float x0 = fmaf(a00, b0, 1.f), x1 = fmaf(a01, b1, 1.f);
          float x2 = fmaf(a02, b2, 1.f), x3 = fmaf(a03, b3, 1.f);
          float p01 = x0 * x1, p23 = x2 * x3;
          float n01 = fmaf(v0, x1, v1 * x0);
          float n23 = fmaf(v2, x3, v3 * x2);
          float num = fmaf(n01, p23, n23 * p01);
          s0 = fmaf(num, frcp(p01 * p23), s0);
        }
        {  // row 1
          float x0 = fmaf(a10, b0, 1.f), x1 = fmaf(a11, b1, 1.f);
          float x2 = fmaf(a12, b2, 1.f), x3 = fmaf(a13, b3, 1.f);
          float p01 = x0 * x1, p23 = x2 * x3;
          float n01 = fmaf(v0, x1, v1 * x0);
          float n23 = fmaf(v2, x3, v3 * x2);
          float num = fmaf(n01, p23, n23 * p01);
          s1 = fmaf(num, frcp(p01 * p23), s1);
        }
      }
    }
    S0[kt] = s0;
    S1[kt] = s1;
    if (kt < 3) {
      __syncthreads();  // all reads of Bt done
      K2_WRITE();       // vmcnt wait inserted by compiler
      __syncthreads();  // Bt ready
    }
  }
#undef K2_LOADS
#undef K2_WRITE

  // softmax over k of (-2S): max(score) <-> min(S). Rows span 2 waves (k-halves).
  float mn0 = fminf(fminf(S0[0], S0[1]), fminf(S0[2], S0[3]));
  float mn1 = fminf(fminf(S1[0], S1[1]), fminf(S1[2], S1[3]));
#pragma unroll
  for (int off = 32; off > 0; off >>= 1) {
    mn0 = fminf(mn0, __shfl_xor(mn0, off));
    mn1 = fminf(mn1, __shfl_xor(mn1, off));
  }
  if (lane == 0) { red[wav][0] = mn0; red[wav][1] = mn1; }
  __syncthreads();
  mn0 = fminf(red[wav][0], red[wav ^ 1][0]);
  mn1 = fminf(red[wav][1], red[wav ^ 1][1]);
  __syncthreads();  // before red reuse

  float P0[4], P1[4];
  float sum0 = 0.f, sum1 = 0.f;
#pragma unroll
  for (int kt = 0; kt < 4; ++kt) {
    P0[kt] = fexp2((mn0 - S0[kt]) * TWO_LOG2E);
    P1[kt] = fexp2((mn1 - S1[kt]) * TWO_LOG2E);
    sum0 += P0[kt];
    sum1 += P1[kt];
  }
#pragma unroll
  for (int off = 32; off > 0; off >>= 1) {
    sum0 += __shfl_xor(sum0, off);
    sum1 += __shfl_xor(sum1, off);
  }
  if (lane == 0) { red[wav][0] = sum0; red[wav][1] = sum1; }
  __syncthreads();
  float r0 = frcp(red[wav][0] + red[wav ^ 1][0]);
  float r1 = frcp(red[wav][1] + red[wav ^ 1][1]);

  const int row0 = (b * 512 + qbase + rp * 2) * 512;
#pragma unroll
  for (int kt = 0; kt < 4; ++kt) {
    int kcol = kt * 128 + kh * 64 + lane;
    attn[row0 + kcol] = P0[kt] * r0;
    attn[row0 + 512 + kcol] = P1[kt] * r1;
  }
}

// ---------------------------------------------------------------------------
// K3: context[b] = attn[b] @ value[b] via bf16 MFMA 16x16x32.
// Tile 64x64, BK=64, 4 waves (2x2), wave tile 32x32 (2x2 frags).
// grid (8,8,8), block 256.
// ---------------------------------------------------------------------------
__global__ __launch_bounds__(256) void k_context_mfma(
    const float* __restrict__ attn, const unsigned short* __restrict__ valT,
    float* __restrict__ ctx) {
  __shared__ __align__(16) char At[64 * 128];  // [m][k] bf16 swizzled, 8KB
  __shared__ __align__(16) char Bt[64 * 128];  // [n][k] bf16 swizzled, 8KB

  const int t = threadIdx.x;
  const int b = blockIdx.z;
  const int m0 = blockIdx.y * 64, n0 = blockIdx.x * 64;
  const int w = t >> 6, l = t & 63;
  const int wr = w >> 1, wc = w & 1;

  f32x4v acc[2][2];
  acc[0][0] = 0; acc[0][1] = 0; acc[1][0] = 0; acc[1][1] = 0;

  const int sr = t >> 2;
  const int sg = (t & 3);
  const int sswz = sr & 7;

  for (int k0 = 0; k0 < 512; k0 += 64) {
    if (k0) __syncthreads();
    {  // stage A: 16 f32 -> 16 bf16 per thread
      const float* src = &attn[(b * 512 + m0 + sr) * 512 + k0 + sg * 16];
      char* dst = At + sr * 128;
#pragma unroll
      for (int h = 0; h < 2; ++h) {
        float4 f0 = *(const float4*)(src + h * 8);
        float4 f1 = *(const float4*)(src + h * 8 + 4);
        uint4 p = make_uint4(pack2bf(f0.x, f0.y), pack2bf(f0.z, f0.w),
                             pack2bf(f1.x, f1.y), pack2bf(f1.z, f1.w));
        int g = sg * 2 + h;
        *(uint4*)(dst + ((g ^ sswz) << 4)) = p;
      }
      // stage B^T: 32 bf16 per thread (already bf16)
      const unsigned short* srcb = &valT[(b * 512 + n0 + sr) * 512 + k0];
      char* dstb = Bt + sr * 128;
#pragma unroll
      for (int h = 0; h < 2; ++h) {
        int g = sg + h * 4;
        uint4 vb = *(const uint4*)(srcb + g * 8);
        *(uint4*)(dstb + ((g ^ sswz) << 4)) = vb;
      }
    }
    __syncthreads();
#pragma unroll
    for (int ks = 0; ks < 2; ++ks) {
      const int gb = ks * 4 + (l >> 4);
      short8 af[2], bf_[2];
#pragma unroll
      for (int mi = 0; mi < 2; ++mi) {
        int ra = wr * 32 + mi * 16 + (l & 15);
        af[mi] = *(const short8*)(At + ra * 128 + ((gb ^ (ra & 7)) << 4));
      }
#pragma unroll
      for (int ni = 0; ni < 2; ++ni) {
        int rb = wc * 32 + ni * 16 + (l & 15);
        bf_[ni] = *(const short8*)(Bt + rb * 128 + ((gb ^ (rb & 7)) << 4));
      }
#pragma unroll
      for (int mi = 0; mi < 2; ++mi)
#pragma unroll
        for (int ni = 0; ni < 2; ++ni)
          acc[mi][ni] = __builtin_amdgcn_mfma_f32_16x16x32_bf16(
              af[mi], bf_[ni], acc[mi][ni], 0, 0, 0);
    }
  }
  __syncthreads();
#pragma unroll
  for (int mi = 0; mi < 2; ++mi)
#pragma unroll
    for (int ni = 0; ni < 2; ++ni) {
      int col = n0 + wc * 32 + ni * 16 + (l & 15);
#pragma unroll
      for (int j = 0; j < 4; ++j) {
        int row = m0 + wr * 32 + mi * 16 + (l >> 4) * 4 + j;
        ctx[(b * 512 + row) * 512 + col] = acc[mi][ni][j];
      }
    }
}

extern "C" void kernel_launch(void* const* d_in, const int* in_sizes, int n_in,
                              void* d_out, int out_size, void* d_ws, size_t ws_size,
                              hipStream_t stream) {
  const float* query = (const float*)d_in[0];
  const float* key   = (const float*)d_in[1];
  const float* value = (const float*)d_in[2];
  const float* w1    = (const float*)d_in[3];
  const float* w2    = (const float*)d_in[4];
  const float* v     = (const float*)d_in[5];

  float* attn = (float*)d_out;
  float* ctx  = attn + 8 * 512 * 512;

  float* Aexp = (float*)d_ws;                                   // 4096*128 f32
  unsigned short* Bexp = (unsigned short*)(Aexp + 4096 * 128);  // 4096*128 bf16
  unsigned short* valT = Bexp + 4096 * 128;                     // 8*512*512 bf16

  k_proj_mfma<<<dim3(128, 2, 2), 256, 0, stream>>>(query, key, w1, w2, Aexp, Bexp);
  k_valT<<<dim3(8, 8, 8), 256, 0, stream>>>(value, valT);
  k_score_softmax<<<dim3(128, 8), 256, 0, stream>>>(Aexp, Bexp, v, attn);
  k_context_mfma<<<dim3(8, 8, 8), 256, 0, stream>>>(attn, valT, ctx);
}